// Round 11
// baseline (100.225 us; speedup 1.0000x reference)
//
#include <hip/hip_runtime.h>
#include <cstdint>

// ChamferLoss on MI355X — MFMA edition v6 (MEASUREMENT ROUND).
// Identical math/structure to R10 (best: 45.0us). nn_mfma body repeated
// REP_NN=3 times, combine body REP_CB=8 times — idempotent (same values
// rewritten), deterministic, graph-safe. Purpose: push my dispatches above
// the ~39us harness poison-fills so rocprof top-5 finally shows THEIR
// dur/VGPR/Occupancy/MfmaUtil/VALUBusy/bank-conflict counters.
// True per-kernel cost: nn = dispatch_dur/3, combine = dispatch_dur/8.

#define REP_NN 3
#define REP_CB 8

#define BLK 256
#define CHUNK 512          // targets staged per buffer (32KB total LDS)
#define NQTR 1024          // targets per block (quarter of N)
#define FLT_BIG 3.402823466e38f

typedef _Float16 f16x8 __attribute__((ext_vector_type(8)));
typedef float    f32x16 __attribute__((ext_vector_type(16)));

__device__ __forceinline__ unsigned int f2mono(float f) {
    unsigned int u = __float_as_uint(f);
    return (u & 0x80000000u) ? ~u : (u | 0x80000000u);
}

__device__ __forceinline__ void fsplit(float v, _Float16& h, _Float16& l) {
    h = (_Float16)v;
    l = (_Float16)(v - (float)h);
}

__device__ __forceinline__ float min3f(float a, float b, float c) {
    float d;
    asm("v_min3_f32 %0, %1, %2, %3" : "=v"(d) : "v"(a), "v"(b), "v"(c));
    return d;
}

// Fold 16 acc values (min3 tree, 8 ops) + (best, group) update (3 ops).
__device__ __forceinline__ void fold1(const f32x16& c, float& best, int& bg, int g) {
    float t0 = min3f(c[0], c[1], c[2]);
    float t1 = min3f(c[3], c[4], c[5]);
    float t2 = min3f(c[6], c[7], c[8]);
    float t3 = min3f(c[9], c[10], c[11]);
    float t4 = min3f(c[12], c[13], c[14]);
    float u0 = min3f(t0, t1, c[15]);
    float u1 = min3f(t2, t3, t4);
    float v  = fminf(u0, u1);
    bool lt = v < best;              // strict: earliest group on tie
    bg   = lt ? g : bg;
    best = lt ? v : best;
}

__device__ __forceinline__ unsigned long long shflxor_u64_32(unsigned long long v) {
    unsigned lo = (unsigned)v, hi = (unsigned)(v >> 32);
    lo = __shfl_xor(lo, 32, 64);
    hi = __shfl_xor(hi, 32, 64);
    return ((unsigned long long)hi << 32) | lo;
}

__global__ __launch_bounds__(BLK) void nn_mfma(
    const float* __restrict__ K1, const float* __restrict__ K2,
    unsigned long long* __restrict__ pkeys)
{
    // grid 1024: qtr(4) | mtile(8) | b(16) | dir(2)
    int bid = blockIdx.x;
    int qtr = bid & 3;
    int mt  = (bid >> 2) & 7;
    int b   = (bid >> 5) & 15;
    int dir = bid >> 9;

    const float* Qp = dir ? K2 : K1;
    const float* Tp = dir ? K1 : K2;
    const float* Qb = Qp + (size_t)b * 3 * 4096;
    const float* Tb = Tp + (size_t)b * 3 * 4096;

    __shared__ f16x8 sA[2][CHUNK / 32][64];   // 32 KB

    const int tid = threadIdx.x;
    const int l   = tid & 63;
    const int wid = tid >> 6;
    const int c31 = l & 31;
    const int lh  = l >> 5;

    // ---- per-lane query B-frags: 4 per wave = 128 queries (verified layout) ----
    const int mBase = mt * 512 + wid * 128;
    f16x8 bq[4];
#pragma unroll
    for (int qs = 0; qs < 4; ++qs) {
        int m = mBase + qs * 32 + c31;
        float x = Qb[0 * 4096 + m], y = Qb[1 * 4096 + m], z = Qb[2 * 4096 + m];
        _Float16 Xh, Xl, Yh, Yl, Zh, Zl;
        fsplit(-2.0f * x, Xh, Xl);
        fsplit(-2.0f * y, Yh, Yl);
        fsplit(-2.0f * z, Zh, Zl);
        f16x8 v;
        const _Float16 one = (_Float16)1.0f, zr = (_Float16)0.0f;
        v[0] = lh ? Zh  : Xh;  v[1] = lh ? one : Xl;
        v[2] = lh ? one : Xh;  v[3] = lh ? zr  : Yh;
        v[4] = lh ? zr  : Yl;  v[5] = lh ? zr  : Yh;
        v[6] = lh ? zr  : Zh;  v[7] = lh ? zr  : Zl;
        bq[qs] = v;
    }

    const int nBase = qtr * NQTR;
    float tx[2], ty[2], tz[2];                 // staged-point registers
#define LOADC(cc) _Pragma("unroll")                                          \
    for (int j = 0; j < 2; ++j) { int n_ = nBase + (cc) * CHUNK + tid + j*256; \
        tx[j] = Tb[n_]; ty[j] = Tb[4096 + n_]; tz[j] = Tb[2*4096 + n_]; }
#define WRITEC(pb) _Pragma("unroll")                                         \
    for (int j = 0; j < 2; ++j) { _Float16 xh,xl,yh,yl,zh,zl,wh,wl;          \
        fsplit(tx[j],xh,xl); fsplit(ty[j],yh,yl); fsplit(tz[j],zh,zl);       \
        float w_ = fmaf(tx[j],tx[j],fmaf(ty[j],ty[j],tz[j]*tz[j]));          \
        fsplit(w_,wh,wl);                                                    \
        const _Float16 zr_ = (_Float16)0.0f;                                 \
        f16x8 a0_ = {xh,xh,xl,yh,yh,yl,zh,zh};                               \
        f16x8 a1_ = {zl,wh,wl,zr_,zr_,zr_,zr_,zr_};                          \
        int nc = tid + j*256;                                                \
        sA[pb][nc>>5][nc&31] = a0_; sA[pb][nc>>5][32+(nc&31)] = a1_; }

    for (int rep = 0; rep < REP_NN; ++rep) {   // idempotent measurement loop
        const f32x16 zero = {};
        float best[4] = {FLT_BIG, FLT_BIG, FLT_BIG, FLT_BIG};
        int   bg[4]   = {0, 0, 0, 0};

        LOADC(0); WRITEC(0);
        __syncthreads();

        for (int c = 0; c < 2; ++c) {
            const int p = c & 1;
            const int g0 = qtr * 32 + c * 16;  // global group-of-32 base
            if (c < 1) LOADC(1);               // HBM latency hides under MFMAs

            // compiler-scheduled tile loop: 1 ds_read + 4 MFMA + 4 folds
#pragma unroll 2
            for (int t = 0; t < CHUNK / 32; ++t) {
                f16x8 a = sA[p][t][l];         // ds_read_b128
                f32x16 c0 = __builtin_amdgcn_mfma_f32_32x32x16_f16(a, bq[0], zero, 0, 0, 0);
                f32x16 c1 = __builtin_amdgcn_mfma_f32_32x32x16_f16(a, bq[1], zero, 0, 0, 0);
                f32x16 c2 = __builtin_amdgcn_mfma_f32_32x32x16_f16(a, bq[2], zero, 0, 0, 0);
                f32x16 c3 = __builtin_amdgcn_mfma_f32_32x32x16_f16(a, bq[3], zero, 0, 0, 0);
                fold1(c0, best[0], bg[0], g0 + t);
                fold1(c1, best[1], bg[1], g0 + t);
                fold1(c2, best[2], bg[2], g0 + t);
                fold1(c3, best[3], bg[3], g0 + t);
            }

            if (c < 1) WRITEC(p ^ 1);          // other buffer; reads of it done
            __syncthreads();
        }

        // ---- merge lane^32; store 2 keys/lane (coalesced) ----
        unsigned long long kk[4];
#pragma unroll
        for (int qs = 0; qs < 4; ++qs) {
            unsigned long long k = ((unsigned long long)f2mono(best[qs]) << 32) |
                                   (unsigned)bg[qs];
            unsigned long long o = shflxor_u64_32(k);
            kk[qs] = (o < k) ? o : k;          // both halves now hold the min
        }
        unsigned long long* dst = pkeys + ((size_t)(dir * 4 + qtr)) * 65536 +
                                  (size_t)b * 4096 + mBase;
        dst[(2 * lh) * 32 + c31]     = lh ? kk[2] : kk[0];
        dst[(2 * lh + 1) * 32 + c31] = lh ? kk[3] : kk[1];
        __syncthreads();                       // rep boundary: stores done
    }
}

__global__ __launch_bounds__(BLK) void combine_kernel(
    const unsigned long long* __restrict__ pkeys,
    const float* __restrict__ K1, const float* __restrict__ K2,
    const float* __restrict__ s1, const float* __restrict__ s2,
    float* __restrict__ partials)
{
    int gid = blockIdx.x * BLK + (int)threadIdx.x;   // 0..131071
    int dir = gid >> 16;
    int qq  = gid & 65535;
    int b   = qq >> 12, m = qq & 4095;

    const float* Qp = dir ? K2 : K1;
    const float* Tp = dir ? K1 : K2;
    const float* sQ = dir ? s2 : s1;
    const float* sT = dir ? s1 : s2;
    const float scale = 1.0f / 65536.0f;

    __shared__ float red[BLK];

    for (int rep = 0; rep < REP_CB; ++rep) {   // idempotent measurement loop
        // 4-way merge of quarter keys (coalesced u64 loads).
        unsigned long long key = 0xFFFFFFFFFFFFFFFFULL;
#pragma unroll
        for (int q = 0; q < 4; ++q) {
            unsigned long long k = pkeys[(size_t)(dir * 4 + q) * 65536 + qq];
            key = (k < key) ? k : key;
        }
        int g = (int)(key & 0xFFFFFFFFu);

        const float* Qb = Qp + (size_t)b * 3 * 4096;
        const float* Tb = Tp + (size_t)b * 3 * 4096;
        float x = Qb[m], y = Qb[4096 + m], z = Qb[2 * 4096 + m];
        float X = -2.0f * x, Y = -2.0f * y, Z = -2.0f * z;
        float sq1 = fmaf(x, x, fmaf(y, y, z * z));

        // Exact-fp32 serial scan of the winning 32-group; strict < gives
        // first-occurrence argmin. n0 is 128B-aligned -> float4 loads.
        int n0 = g * 32;
        const float4* Tx4 = (const float4*)(Tb + n0);
        const float4* Ty4 = (const float4*)(Tb + 4096 + n0);
        const float4* Tz4 = (const float4*)(Tb + 2 * 4096 + n0);
        float beste = FLT_BIG;
        int bi = n0;
#pragma unroll
        for (int j = 0; j < 8; ++j) {
            float4 xv = Tx4[j], yv = Ty4[j], zv = Tz4[j];
#pragma unroll
            for (int k = 0; k < 4; ++k) {
                float txv = ((const float*)&xv)[k];
                float tyv = ((const float*)&yv)[k];
                float tzv = ((const float*)&zv)[k];
                float w = fmaf(txv, txv, fmaf(tyv, tyv, tzv * tzv));
                float e = fmaf(txv, X, fmaf(tyv, Y, fmaf(tzv, Z, w)));
                bool lt = e < beste;
                bi    = lt ? (n0 + j * 4 + k) : bi;
                beste = lt ? e : beste;
            }
        }

        float d2 = fmaxf(sq1 + beste, 1e-12f);       // reference EPS clamp
        float s = 0.5f * (sQ[qq] + sT[b * 4096 + bi]);
        float v = (logf(s) + sqrtf(d2) / s) * scale;

        red[threadIdx.x] = v;
        __syncthreads();
        for (int st = BLK / 2; st > 0; st >>= 1) {
            if ((int)threadIdx.x < st) red[threadIdx.x] += red[threadIdx.x + st];
            __syncthreads();
        }
        if (threadIdx.x == 0) partials[blockIdx.x] = red[0];
        __syncthreads();                       // rep boundary
    }
}

__global__ __launch_bounds__(256) void final_reduce(
    const float* __restrict__ partials, float* __restrict__ out, int n)
{
    __shared__ float red[256];
    int t = threadIdx.x;
    float a = 0.0f;
    for (int i = t; i < n; i += 256) a += partials[i];
    red[t] = a;
    __syncthreads();
    for (int st = 128; st > 0; st >>= 1) {
        if (t < st) red[t] += red[t + st];
        __syncthreads();
    }
    if (t == 0) out[0] = red[0];
}

extern "C" void kernel_launch(void* const* d_in, const int* in_sizes, int n_in,
                              void* d_out, int out_size, void* d_ws, size_t ws_size,
                              hipStream_t stream) {
    const float* k1 = (const float*)d_in[0];   // (B,3,M)
    const float* k2 = (const float*)d_in[1];   // (B,3,N)
    const float* s1 = (const float*)d_in[2];   // (B,M)
    const float* s2 = (const float*)d_in[3];   // (B,N)
    float* out = (float*)d_out;

    unsigned long long* pkeys = (unsigned long long*)d_ws;   // 8 * 65536 keys
    float* partials = (float*)(pkeys + (size_t)8 * 65536);   // 512 floats

    nn_mfma<<<1024, BLK, 0, stream>>>(k1, k2, pkeys);
    combine_kernel<<<512, BLK, 0, stream>>>(pkeys, k1, k2, s1, s2, partials);
    final_reduce<<<1, 256, 0, stream>>>(partials, out, 512);
}

// Round 13
// 44.496 us; speedup vs baseline: 2.2524x; 2.2524x over previous
//
#include <hip/hip_runtime.h>
#include <cstdint>

// ChamferLoss on MI355X — MFMA edition v8.
// = R10 exactly (last passing config, 45.0us) with ONE change: fold1 uses a
// plain fminf tree instead of inline-asm v_min3 with "v" constraints.
// Rationale (R11 counters: VALUBusy 90%, MfmaUtil 23%, VGPR=68): the asm
// "v" constraints forced all 16 MFMA accumulator values into arch-VGPRs
// (v_accvgpr_read per value) before every fold. Plain fminf lets the
// compiler read AGPRs directly on the gfx950 unified RF and fuse to
// v_min3_f32 itself. R12's __launch_bounds__(256,4) broke numerics
// (unexplained miscompile) -> NOT shipped.
//   nn_mfma: e[m,n] = ||t||^2 - 2 q.t as K=16 f16 GEMM via
//     v_mfma_f32_32x32x16_f16, hi/lo f16 split (11 K-slots, fp32 accumulate,
//     |err|~2e-5; layout verified absmax=0.0 since R6). 4 B-frags per wave
//     (128 queries): per tile 1 ds_read + 4 MFMA + 4 folds. Grid 1024,
//     CHUNK=512 double-buffered (32KB LDS).
//   combine: per-thread 4-way key merge + exact-fp32 scan of the winning
//     32-group (float4 loads), EPS clamp, sqrt, sigma gather, partials.
//   final_reduce: sums 512 partials -> d_out.

#define BLK 256
#define CHUNK 512          // targets staged per buffer (32KB total LDS)
#define NQTR 1024          // targets per block (quarter of N)
#define FLT_BIG 3.402823466e38f

typedef _Float16 f16x8 __attribute__((ext_vector_type(8)));
typedef float    f32x16 __attribute__((ext_vector_type(16)));

__device__ __forceinline__ unsigned int f2mono(float f) {
    unsigned int u = __float_as_uint(f);
    return (u & 0x80000000u) ? ~u : (u | 0x80000000u);
}

__device__ __forceinline__ void fsplit(float v, _Float16& h, _Float16& l) {
    h = (_Float16)v;
    l = (_Float16)(v - (float)h);
}

// Fold 16 acc values (fminf tree shaped for v_min3 fusion; compiler-chosen
// registers so AGPR sources need no explicit copies) + (best,group) update.
__device__ __forceinline__ void fold1(const f32x16& c, float& best, int& bg, int g) {
    float t0 = fminf(fminf(c[0], c[1]), c[2]);
    float t1 = fminf(fminf(c[3], c[4]), c[5]);
    float t2 = fminf(fminf(c[6], c[7]), c[8]);
    float t3 = fminf(fminf(c[9], c[10]), c[11]);
    float t4 = fminf(fminf(c[12], c[13]), c[14]);
    float u0 = fminf(fminf(t0, t1), c[15]);
    float u1 = fminf(fminf(t2, t3), t4);
    float v  = fminf(u0, u1);
    bool lt = v < best;              // strict: earliest group on tie
    bg   = lt ? g : bg;
    best = lt ? v : best;
}

__device__ __forceinline__ unsigned long long shflxor_u64_32(unsigned long long v) {
    unsigned lo = (unsigned)v, hi = (unsigned)(v >> 32);
    lo = __shfl_xor(lo, 32, 64);
    hi = __shfl_xor(hi, 32, 64);
    return ((unsigned long long)hi << 32) | lo;
}

__global__ __launch_bounds__(BLK) void nn_mfma(
    const float* __restrict__ K1, const float* __restrict__ K2,
    unsigned long long* __restrict__ pkeys)
{
    // grid 1024: qtr(4) | mtile(8) | b(16) | dir(2)
    int bid = blockIdx.x;
    int qtr = bid & 3;
    int mt  = (bid >> 2) & 7;
    int b   = (bid >> 5) & 15;
    int dir = bid >> 9;

    const float* Qp = dir ? K2 : K1;
    const float* Tp = dir ? K1 : K2;
    const float* Qb = Qp + (size_t)b * 3 * 4096;
    const float* Tb = Tp + (size_t)b * 3 * 4096;

    __shared__ f16x8 sA[2][CHUNK / 32][64];   // 32 KB

    const int tid = threadIdx.x;
    const int l   = tid & 63;
    const int wid = tid >> 6;
    const int c31 = l & 31;
    const int lh  = l >> 5;

    // ---- per-lane query B-frags: 4 per wave = 128 queries (verified layout) ----
    const int mBase = mt * 512 + wid * 128;
    f16x8 bq[4];
#pragma unroll
    for (int qs = 0; qs < 4; ++qs) {
        int m = mBase + qs * 32 + c31;
        float x = Qb[0 * 4096 + m], y = Qb[1 * 4096 + m], z = Qb[2 * 4096 + m];
        _Float16 Xh, Xl, Yh, Yl, Zh, Zl;
        fsplit(-2.0f * x, Xh, Xl);
        fsplit(-2.0f * y, Yh, Yl);
        fsplit(-2.0f * z, Zh, Zl);
        f16x8 v;
        const _Float16 one = (_Float16)1.0f, zr = (_Float16)0.0f;
        v[0] = lh ? Zh  : Xh;  v[1] = lh ? one : Xl;
        v[2] = lh ? one : Xh;  v[3] = lh ? zr  : Yh;
        v[4] = lh ? zr  : Yl;  v[5] = lh ? zr  : Yh;
        v[6] = lh ? zr  : Zh;  v[7] = lh ? zr  : Zl;
        bq[qs] = v;
    }

    const f32x16 zero = {};
    float best[4] = {FLT_BIG, FLT_BIG, FLT_BIG, FLT_BIG};
    int   bg[4]   = {0, 0, 0, 0};
    const int nBase = qtr * NQTR;

    float tx[2], ty[2], tz[2];                 // staged-point registers
#define LOADC(cc) _Pragma("unroll")                                          \
    for (int j = 0; j < 2; ++j) { int n_ = nBase + (cc) * CHUNK + tid + j*256; \
        tx[j] = Tb[n_]; ty[j] = Tb[4096 + n_]; tz[j] = Tb[2*4096 + n_]; }
#define WRITEC(pb) _Pragma("unroll")                                         \
    for (int j = 0; j < 2; ++j) { _Float16 xh,xl,yh,yl,zh,zl,wh,wl;          \
        fsplit(tx[j],xh,xl); fsplit(ty[j],yh,yl); fsplit(tz[j],zh,zl);       \
        float w_ = fmaf(tx[j],tx[j],fmaf(ty[j],ty[j],tz[j]*tz[j]));          \
        fsplit(w_,wh,wl);                                                    \
        const _Float16 zr_ = (_Float16)0.0f;                                 \
        f16x8 a0_ = {xh,xh,xl,yh,yh,yl,zh,zh};                               \
        f16x8 a1_ = {zl,wh,wl,zr_,zr_,zr_,zr_,zr_};                          \
        int nc = tid + j*256;                                                \
        sA[pb][nc>>5][nc&31] = a0_; sA[pb][nc>>5][32+(nc&31)] = a1_; }

    LOADC(0); WRITEC(0);
    __syncthreads();

    for (int c = 0; c < 2; ++c) {
        const int p = c & 1;
        const int g0 = qtr * 32 + c * 16;      // global group-of-32 base
        if (c < 1) LOADC(1);                   // HBM latency hides under MFMAs

        // compiler-scheduled tile loop: 1 ds_read + 4 MFMA + 4 folds
#pragma unroll 2
        for (int t = 0; t < CHUNK / 32; ++t) {
            f16x8 a = sA[p][t][l];             // ds_read_b128
            f32x16 c0 = __builtin_amdgcn_mfma_f32_32x32x16_f16(a, bq[0], zero, 0, 0, 0);
            f32x16 c1 = __builtin_amdgcn_mfma_f32_32x32x16_f16(a, bq[1], zero, 0, 0, 0);
            f32x16 c2 = __builtin_amdgcn_mfma_f32_32x32x16_f16(a, bq[2], zero, 0, 0, 0);
            f32x16 c3 = __builtin_amdgcn_mfma_f32_32x32x16_f16(a, bq[3], zero, 0, 0, 0);
            fold1(c0, best[0], bg[0], g0 + t);
            fold1(c1, best[1], bg[1], g0 + t);
            fold1(c2, best[2], bg[2], g0 + t);
            fold1(c3, best[3], bg[3], g0 + t);
        }

        if (c < 1) WRITEC(p ^ 1);              // other buffer; reads of it done
        __syncthreads();
    }

    // ---- merge lane^32 (same query column, other row-half); store 2/lane ----
    unsigned long long kk[4];
#pragma unroll
    for (int qs = 0; qs < 4; ++qs) {
        unsigned long long k = ((unsigned long long)f2mono(best[qs]) << 32) |
                               (unsigned)bg[qs];
        unsigned long long o = shflxor_u64_32(k);
        kk[qs] = (o < k) ? o : k;              // both halves now hold the min
    }
    unsigned long long* dst = pkeys + ((size_t)(dir * 4 + qtr)) * 65536 +
                              (size_t)b * 4096 + mBase;
    // lane (lh, c31) stores query sets qs = 2*lh and 2*lh+1 (coalesced).
    dst[(2 * lh) * 32 + c31]     = lh ? kk[2] : kk[0];
    dst[(2 * lh + 1) * 32 + c31] = lh ? kk[3] : kk[1];
}

__global__ __launch_bounds__(BLK) void combine_kernel(
    const unsigned long long* __restrict__ pkeys,
    const float* __restrict__ K1, const float* __restrict__ K2,
    const float* __restrict__ s1, const float* __restrict__ s2,
    float* __restrict__ partials)
{
    int gid = blockIdx.x * BLK + (int)threadIdx.x;   // 0..131071
    int dir = gid >> 16;
    int qq  = gid & 65535;
    int b   = qq >> 12, m = qq & 4095;

    const float* Qp = dir ? K2 : K1;
    const float* Tp = dir ? K1 : K2;
    const float* sQ = dir ? s2 : s1;
    const float* sT = dir ? s1 : s2;
    const float scale = 1.0f / 65536.0f;

    // 4-way merge of quarter keys (coalesced u64 loads).
    unsigned long long key = 0xFFFFFFFFFFFFFFFFULL;
#pragma unroll
    for (int q = 0; q < 4; ++q) {
        unsigned long long k = pkeys[(size_t)(dir * 4 + q) * 65536 + qq];
        key = (k < key) ? k : key;
    }
    int g = (int)(key & 0xFFFFFFFFu);

    const float* Qb = Qp + (size_t)b * 3 * 4096;
    const float* Tb = Tp + (size_t)b * 3 * 4096;
    float x = Qb[m], y = Qb[4096 + m], z = Qb[2 * 4096 + m];
    float X = -2.0f * x, Y = -2.0f * y, Z = -2.0f * z;
    float sq1 = fmaf(x, x, fmaf(y, y, z * z));

    // Exact-fp32 serial scan of the winning 32-group; strict < gives
    // first-occurrence argmin. n0 is 128B-aligned -> float4 loads.
    int n0 = g * 32;
    const float4* Tx4 = (const float4*)(Tb + n0);
    const float4* Ty4 = (const float4*)(Tb + 4096 + n0);
    const float4* Tz4 = (const float4*)(Tb + 2 * 4096 + n0);
    float beste = FLT_BIG;
    int bi = n0;
#pragma unroll
    for (int j = 0; j < 8; ++j) {
        float4 xv = Tx4[j], yv = Ty4[j], zv = Tz4[j];
#pragma unroll
        for (int k = 0; k < 4; ++k) {
            float txv = ((const float*)&xv)[k];
            float tyv = ((const float*)&yv)[k];
            float tzv = ((const float*)&zv)[k];
            float w = fmaf(txv, txv, fmaf(tyv, tyv, tzv * tzv));
            float e = fmaf(txv, X, fmaf(tyv, Y, fmaf(tzv, Z, w)));
            bool lt = e < beste;
            bi    = lt ? (n0 + j * 4 + k) : bi;
            beste = lt ? e : beste;
        }
    }

    float d2 = fmaxf(sq1 + beste, 1e-12f);           // reference EPS clamp
    float s = 0.5f * (sQ[qq] + sT[b * 4096 + bi]);
    float v = (logf(s) + sqrtf(d2) / s) * scale;

    __shared__ float red[BLK];
    red[threadIdx.x] = v;
    __syncthreads();
    for (int st = BLK / 2; st > 0; st >>= 1) {
        if ((int)threadIdx.x < st) red[threadIdx.x] += red[threadIdx.x + st];
        __syncthreads();
    }
    if (threadIdx.x == 0) partials[blockIdx.x] = red[0];
}

__global__ __launch_bounds__(256) void final_reduce(
    const float* __restrict__ partials, float* __restrict__ out, int n)
{
    __shared__ float red[256];
    int t = threadIdx.x;
    float a = 0.0f;
    for (int i = t; i < n; i += 256) a += partials[i];
    red[t] = a;
    __syncthreads();
    for (int st = 128; st > 0; st >>= 1) {
        if (t < st) red[t] += red[t + st];
        __syncthreads();
    }
    if (t == 0) out[0] = red[0];
}

extern "C" void kernel_launch(void* const* d_in, const int* in_sizes, int n_in,
                              void* d_out, int out_size, void* d_ws, size_t ws_size,
                              hipStream_t stream) {
    const float* k1 = (const float*)d_in[0];   // (B,3,M)
    const float* k2 = (const float*)d_in[1];   // (B,3,N)
    const float* s1 = (const float*)d_in[2];   // (B,M)
    const float* s2 = (const float*)d_in[3];   // (B,N)
    float* out = (float*)d_out;

    unsigned long long* pkeys = (unsigned long long*)d_ws;   // 8 * 65536 keys
    float* partials = (float*)(pkeys + (size_t)8 * 65536);   // 512 floats

    nn_mfma<<<1024, BLK, 0, stream>>>(k1, k2, pkeys);
    combine_kernel<<<512, BLK, 0, stream>>>(pkeys, k1, k2, s1, s2, partials);
    final_reduce<<<1, 256, 0, stream>>>(partials, out, 512);
}